// Round 2
// baseline (130.096 us; speedup 1.0000x reference)
//
#include <hip/hip_runtime.h>
#include <stdint.h>

#define N_ROWS 65536
#define D_IN   1024
#define NBIT   64
#define LN_EPS 1e-5f

typedef __attribute__((ext_vector_type(8))) _Float16 f16x8;
typedef __attribute__((ext_vector_type(4))) float f32x4;

// ---------------- kernel 0: prep split-W fragments + per-bit constants ----------------
// Fragment layout (same as validated round-0): idx = (((kt*4+nt)*64 + g*16 + bl)*8 + j)
//   bit = nt*16 + bl,  d = kt*32 + g*8 + j
// whi = fp16(gw);  wlo = fp16((gw - whi) * 2048)   [exact split, lo scaled to stay normal]
// u[bit] = sum_d g1[d]*W[bit][d];  v[bit] = sum_d b1[d]*W[bit][d] + bias[bit]
__global__ void prep_kernel(const float* __restrict__ W, const float* __restrict__ bias,
                            const float* __restrict__ g1, const float* __restrict__ b1,
                            _Float16* __restrict__ whi, _Float16* __restrict__ wlo,
                            float* __restrict__ u, float* __restrict__ v) {
    int bit = blockIdx.x;            // 0..63
    int t   = threadIdx.x;           // 0..255
    int nt  = bit >> 4, bl = bit & 15;
    float su = 0.f, sv = 0.f;
    for (int d = t; d < D_IN; d += 256) {
        float w  = W[bit * D_IN + d];
        float gw = w * g1[d];
        su += gw;
        sv += w * b1[d];
        int kt = d >> 5, gg = (d >> 3) & 3, j = d & 7;
        size_t idx = (((size_t)(kt * 4 + nt)) * 64 + gg * 16 + bl) * 8 + j;
        _Float16 h = (_Float16)gw;
        whi[idx] = h;
        wlo[idx] = (_Float16)((gw - (float)h) * 2048.0f);
    }
    __shared__ float s1[256], s2[256];
    s1[t] = su; s2[t] = sv;
    __syncthreads();
    for (int off = 128; off > 0; off >>= 1) {
        if (t < off) { s1[t] += s1[t + off]; s2[t] += s2[t + off]; }
        __syncthreads();
    }
    if (t == 0) { u[bit] = s1[0]; v[bit] = s2[0] + bias[bit]; }
}

// ---------------- kernel 1: fused LN1 + split-fp16 GEMM + LN2 + partial col sums ----------------
// 1 wave = 16 rows; block = 4 waves = 64 rows; grid = 1024 blocks.
__global__ void __launch_bounds__(256) main_kernel(
        const float* __restrict__ X,
        const _Float16* __restrict__ whi, const _Float16* __restrict__ wlo,
        const float* __restrict__ u, const float* __restrict__ v,
        const float* __restrict__ g2, const float* __restrict__ b2,
        float* __restrict__ L, float* __restrict__ P) {
    int tid  = threadIdx.x;
    int wid  = tid >> 6, lane = tid & 63;
    int g    = lane >> 4, r16 = lane & 15;
    int row_base = blockIdx.x * 64 + wid * 16;

    const float* xrow = X + (size_t)(row_base + r16) * D_IN + g * 8;

    f32x4 acc_h0[4], acc_h1[4], acc_m[4], acc_ll[4];
#pragma unroll
    for (int nt = 0; nt < 4; ++nt) {
        acc_h0[nt] = (f32x4){0.f, 0.f, 0.f, 0.f};
        acc_h1[nt] = (f32x4){0.f, 0.f, 0.f, 0.f};
        acc_m[nt]  = (f32x4){0.f, 0.f, 0.f, 0.f};
        acc_ll[nt] = (f32x4){0.f, 0.f, 0.f, 0.f};
    }
    float sum = 0.f, sumsq = 0.f;

    const _Float16* wfh = whi + (size_t)lane * 8;
    const _Float16* wfl = wlo + (size_t)lane * 8;

#pragma unroll 2
    for (int t2 = 0; t2 < 16; ++t2) {
#pragma unroll
        for (int tt = 0; tt < 2; ++tt) {
            int t = t2 * 2 + tt;
            float4 x0 = *(const float4*)(xrow + t * 32);
            float4 x1 = *(const float4*)(xrow + t * 32 + 4);
            float xs[8] = {x0.x, x0.y, x0.z, x0.w, x1.x, x1.y, x1.z, x1.w};
            f16x8 ahi, alo;
            float ts = 0.f, tq = 0.f;
#pragma unroll
            for (int j = 0; j < 8; ++j) {
                ts += xs[j];
                tq = fmaf(xs[j], xs[j], tq);
                _Float16 h = (_Float16)xs[j];
                ahi[j] = h;
                alo[j] = (_Float16)((xs[j] - (float)h) * 2048.0f);
            }
            sum += ts;
            sumsq += tq;
            const _Float16* wth = wfh + (size_t)t * 2048;
            const _Float16* wtl = wfl + (size_t)t * 2048;
#pragma unroll
            for (int nt = 0; nt < 4; ++nt) {
                f16x8 bh = *(const f16x8*)(wth + nt * 512);
                f16x8 bl = *(const f16x8*)(wtl + nt * 512);
                if (tt == 0)
                    acc_h0[nt] = __builtin_amdgcn_mfma_f32_16x16x32_f16(ahi, bh, acc_h0[nt], 0, 0, 0);
                else
                    acc_h1[nt] = __builtin_amdgcn_mfma_f32_16x16x32_f16(ahi, bh, acc_h1[nt], 0, 0, 0);
                acc_m[nt]  = __builtin_amdgcn_mfma_f32_16x16x32_f16(ahi, bl, acc_m[nt], 0, 0, 0);
                acc_m[nt]  = __builtin_amdgcn_mfma_f32_16x16x32_f16(alo, bh, acc_m[nt], 0, 0, 0);
                acc_ll[nt] = __builtin_amdgcn_mfma_f32_16x16x32_f16(alo, bl, acc_ll[nt], 0, 0, 0);
            }
        }
    }

    // LN1 stats: reduce over the 4 lane-groups sharing a row (xor 16,32)
    sum   += __shfl_xor(sum, 16);   sum   += __shfl_xor(sum, 32);
    sumsq += __shfl_xor(sumsq, 16); sumsq += __shfl_xor(sumsq, 32);
    float mu   = sum * (1.f / 1024.f);
    float var  = sumsq * (1.f / 1024.f) - mu * mu;
    float rstd = rsqrtf(var + LN_EPS);

    // per-bit constants for this lane's 4 columns (bit = nt*16 + r16)
    float uv[4], vv[4], g2v[4], b2v[4];
#pragma unroll
    for (int nt = 0; nt < 4; ++nt) {
        int bitc = nt * 16 + r16;
        uv[nt] = u[bitc]; vv[nt] = v[bitc]; g2v[nt] = g2[bitc]; b2v[nt] = b2[bitc];
    }
    // stats for the 4 rows this lane holds in C (row = g*4 + reg)
    float mu_m[4], rs_m[4];
#pragma unroll
    for (int reg = 0; reg < 4; ++reg) {
        int m = g * 4 + reg;
        mu_m[reg] = __shfl(mu, m);
        rs_m[reg] = __shfl(rstd, m);
    }

    float lg[4][4];  // [nt][reg]
#pragma unroll
    for (int nt = 0; nt < 4; ++nt)
#pragma unroll
        for (int reg = 0; reg < 4; ++reg) {
            float dot = (acc_h0[nt][reg] + acc_h1[nt][reg])
                      + acc_m[nt][reg] * (1.0f / 2048.0f)
                      + acc_ll[nt][reg] * (1.0f / 4194304.0f);
            lg[nt][reg] = rs_m[reg] * dot - rs_m[reg] * mu_m[reg] * uv[nt] + vv[nt];
        }

    // LN2 over the 64 bits of each row
#pragma unroll
    for (int reg = 0; reg < 4; ++reg) {
        float s1 = lg[0][reg] + lg[1][reg] + lg[2][reg] + lg[3][reg];
        float s2 = lg[0][reg]*lg[0][reg] + lg[1][reg]*lg[1][reg]
                 + lg[2][reg]*lg[2][reg] + lg[3][reg]*lg[3][reg];
#pragma unroll
        for (int m = 1; m <= 8; m <<= 1) {
            s1 += __shfl_xor(s1, m);
            s2 += __shfl_xor(s2, m);
        }
        float mean = s1 * (1.f / 64.f);
        float va   = s2 * (1.f / 64.f) - mean * mean;
        float rs2  = rsqrtf(va + LN_EPS);
#pragma unroll
        for (int nt = 0; nt < 4; ++nt)
            lg[nt][reg] = (lg[nt][reg] - mean) * rs2 * g2v[nt] + b2v[nt];
    }

    // store LN2'd logits
#pragma unroll
    for (int reg = 0; reg < 4; ++reg) {
        size_t row = (size_t)(row_base + g * 4 + reg);
#pragma unroll
        for (int nt = 0; nt < 4; ++nt)
            L[row * 64 + nt * 16 + r16] = lg[nt][reg];
    }

    // per-wave column partial sums (for batch mean)
#pragma unroll
    for (int nt = 0; nt < 4; ++nt) {
        float cs = lg[nt][0] + lg[nt][1] + lg[nt][2] + lg[nt][3];
        cs += __shfl_xor(cs, 16);
        cs += __shfl_xor(cs, 32);
        if (g == 0)
            P[((size_t)blockIdx.x * 4 + wid) * 64 + nt * 16 + r16] = cs;
    }
}

// ---------------- kernel 2: reduce column partials -> column means ----------------
__global__ void reduce_kernel(const float* __restrict__ P, float* __restrict__ cm) {
    int bit = blockIdx.x, t = threadIdx.x;
    float s = 0.f;
    for (int p = t; p < 4096; p += 256) s += P[(size_t)p * 64 + bit];
    __shared__ float sh[256];
    sh[t] = s;
    __syncthreads();
    for (int off = 128; off > 0; off >>= 1) {
        if (t < off) sh[t] += sh[t + off];
        __syncthreads();
    }
    if (t == 0) cm[bit] = sh[0] * (1.f / (float)N_ROWS);
}

// ---------------- kernel 3: mean-center + tanh + binarize ----------------
// L lives in the B-half of d_out; each element is read once then overwritten
// by the same thread in the same iteration (deterministic, replay-safe).
__global__ void final_kernel(const float* __restrict__ L, const float* __restrict__ cm,
                             float* __restrict__ out) {
    __shared__ float cms[64];
    if (threadIdx.x < 64) cms[threadIdx.x] = cm[threadIdx.x];
    __syncthreads();
    const float4* L4 = (const float4*)L;
    float4* H4 = (float4*)out;
    float4* B4 = (float4*)(out + (size_t)N_ROWS * NBIT);
    int total = N_ROWS * NBIT / 4;
    for (int i = blockIdx.x * blockDim.x + threadIdx.x; i < total;
         i += gridDim.x * blockDim.x) {
        float4 x = L4[i];
        int bb = (i & 15) * 4;
        float4 h, bo;
        h.x = tanhf(0.5f * (x.x - cms[bb + 0]));
        h.y = tanhf(0.5f * (x.y - cms[bb + 1]));
        h.z = tanhf(0.5f * (x.z - cms[bb + 2]));
        h.w = tanhf(0.5f * (x.w - cms[bb + 3]));
        bo.x = h.x >= 0.f ? 1.f : -1.f;
        bo.y = h.y >= 0.f ? 1.f : -1.f;
        bo.z = h.z >= 0.f ? 1.f : -1.f;
        bo.w = h.w >= 0.f ? 1.f : -1.f;
        H4[i] = h;
        B4[i] = bo;
    }
}

extern "C" void kernel_launch(void* const* d_in, const int* in_sizes, int n_in,
                              void* d_out, int out_size, void* d_ws, size_t ws_size,
                              hipStream_t stream) {
    (void)in_sizes; (void)n_in; (void)out_size; (void)ws_size;
    const float* X  = (const float*)d_in[0];
    const float* W  = (const float*)d_in[1];
    const float* bb = (const float*)d_in[2];
    const float* g1 = (const float*)d_in[3];
    const float* b1 = (const float*)d_in[4];
    const float* g2 = (const float*)d_in[5];
    const float* b2 = (const float*)d_in[6];

    char* ws = (char*)d_ws;
    _Float16* whi = (_Float16*)ws;                 // 128 KiB
    _Float16* wlo = (_Float16*)(ws + 131072);      // 128 KiB
    float* u  = (float*)(ws + 262144);             // 256 B
    float* v  = (float*)(ws + 266240);             // 256 B
    float* P  = (float*)(ws + 270336);             // 1 MiB (4096*64*4)
    float* cm = (float*)(ws + 270336 + 4096 * 64 * 4);

    float* out = (float*)d_out;
    float* L   = out + (size_t)N_ROWS * NBIT;      // reuse B-half of d_out as logit scratch

    prep_kernel<<<64, 256, 0, stream>>>(W, bb, g1, b1, whi, wlo, u, v);
    main_kernel<<<1024, 256, 0, stream>>>(X, whi, wlo, u, v, g2, b2, L, P);
    reduce_kernel<<<64, 256, 0, stream>>>(P, cm);
    final_kernel<<<2048, 256, 0, stream>>>(L, cm, out);
}

// Round 3
// 97.625 us; speedup vs baseline: 1.3326x; 1.3326x over previous
//
#include <hip/hip_runtime.h>
#include <stdint.h>

#define N_ROWS 65536
#define D_IN   1024
#define NBIT   64
#define LN_EPS 1e-5f

typedef __attribute__((ext_vector_type(8))) _Float16 f16x8;
typedef __attribute__((ext_vector_type(4))) float f32x4;

__device__ __forceinline__ void gload_lds16(const void* g, void* l) {
    __builtin_amdgcn_global_load_lds(
        (const __attribute__((address_space(1))) uint32_t*)g,
        (__attribute__((address_space(3))) uint32_t*)l, 16, 0, 0);
}

// ---------------- kernel 0: prep split-W fragments + per-bit constants ----------------
// Fragment layout: idx = (((kt*4+nt)*64 + g*16 + bl)*8 + j)
//   bit = nt*16 + bl,  d = kt*32 + g*8 + j
// whi = fp16(gw);  wlo = fp16((gw - whi) * 2048)   [exact split, lo scaled to stay normal]
__global__ void prep_kernel(const float* __restrict__ W, const float* __restrict__ bias,
                            const float* __restrict__ g1, const float* __restrict__ b1,
                            _Float16* __restrict__ whi, _Float16* __restrict__ wlo,
                            float* __restrict__ u, float* __restrict__ v) {
    int bit = blockIdx.x;            // 0..63
    int t   = threadIdx.x;           // 0..255
    int nt  = bit >> 4, bl = bit & 15;
    float su = 0.f, sv = 0.f;
    for (int d = t; d < D_IN; d += 256) {
        float w  = W[bit * D_IN + d];
        float gw = w * g1[d];
        su += gw;
        sv += w * b1[d];
        int kt = d >> 5, gg = (d >> 3) & 3, j = d & 7;
        size_t idx = (((size_t)(kt * 4 + nt)) * 64 + gg * 16 + bl) * 8 + j;
        _Float16 h = (_Float16)gw;
        whi[idx] = h;
        wlo[idx] = (_Float16)((gw - (float)h) * 2048.0f);
    }
    __shared__ float s1[256], s2[256];
    s1[t] = su; s2[t] = sv;
    __syncthreads();
    for (int off = 128; off > 0; off >>= 1) {
        if (t < off) { s1[t] += s1[t + off]; s2[t] += s2[t + off]; }
        __syncthreads();
    }
    if (t == 0) { u[bit] = s1[0]; v[bit] = s2[0] + bias[bit]; }
}

// ---------------- kernel 1: fused LN1 + split-fp16 GEMM + LN2 + partial col sums ----------------
// 1 wave = 16 rows; block = 4 waves = 64 rows; grid = 1024 blocks.
// W fragments staged to LDS (2 K-steps/chunk, double-buffered, 32 KiB) shared by 4 waves.
__global__ void __launch_bounds__(256) main_kernel(
        const float* __restrict__ X,
        const _Float16* __restrict__ whi, const _Float16* __restrict__ wlo,
        const float* __restrict__ u, const float* __restrict__ v,
        const float* __restrict__ g2, const float* __restrict__ b2,
        float* __restrict__ L, float* __restrict__ P) {
    __shared__ _Float16 lw[2][8192];   // [buf][hi:0..4096 | lo:4096..8192] halves
    int tid  = threadIdx.x;
    int wid  = tid >> 6, lane = tid & 63;
    int g    = lane >> 4, r16 = lane & 15;
    int row_base = blockIdx.x * 64 + wid * 16;

    const float* xrow = X + (size_t)(row_base + r16) * D_IN + g * 8;

    // wave wid stages one 4 KiB quarter of each 16 KiB chunk
    const _Float16* gbase = ((wid & 2) ? wlo : whi) + (wid & 1) * 2048 + lane * 8;
    const int lofs = ((wid & 2) ? 4096 : 0) + (wid & 1) * 2048;

    // prologue: stage chunk 0
#pragma unroll
    for (int r = 0; r < 4; ++r)
        gload_lds16(gbase + r * 512, &lw[0][lofs + r * 512]);

    f32x4 acc_h0[4], acc_h1[4], acc_m[4], acc_ll[4];
#pragma unroll
    for (int nt = 0; nt < 4; ++nt) {
        acc_h0[nt] = (f32x4){0.f, 0.f, 0.f, 0.f};
        acc_h1[nt] = (f32x4){0.f, 0.f, 0.f, 0.f};
        acc_m[nt]  = (f32x4){0.f, 0.f, 0.f, 0.f};
        acc_ll[nt] = (f32x4){0.f, 0.f, 0.f, 0.f};
    }
    float sum = 0.f, sumsq = 0.f;

    __syncthreads();   // compiler-emitted vmcnt(0) drain => chunk 0 staged

    for (int c = 0; c < 16; ++c) {
        const _Float16* lwb = &lw[c & 1][0];
        if (c + 1 < 16) {          // issue next-chunk stage into other buffer
            const _Float16* gs = gbase + (c + 1) * 4096;
            _Float16* ld = &lw[(c + 1) & 1][lofs];
#pragma unroll
            for (int r = 0; r < 4; ++r)
                gload_lds16(gs + r * 512, ld + r * 512);
        }
#pragma unroll
        for (int t2 = 0; t2 < 2; ++t2) {
            int t = c * 2 + t2;
            float4 x0 = *(const float4*)(xrow + t * 32);
            float4 x1 = *(const float4*)(xrow + t * 32 + 4);
            float xs[8] = {x0.x, x0.y, x0.z, x0.w, x1.x, x1.y, x1.z, x1.w};
            f16x8 ahi, alo;
            float ts = 0.f, tq = 0.f;
#pragma unroll
            for (int j = 0; j < 8; ++j) {
                ts += xs[j];
                tq = fmaf(xs[j], xs[j], tq);
                _Float16 h = (_Float16)xs[j];
                ahi[j] = h;
                alo[j] = (_Float16)((xs[j] - (float)h) * 2048.0f);
            }
            sum += ts;
            sumsq += tq;
            const _Float16* bhp = lwb + t2 * 2048 + lane * 8;
#pragma unroll
            for (int nt = 0; nt < 4; ++nt) {
                f16x8 bh = *(const f16x8*)(bhp + nt * 512);
                f16x8 bl = *(const f16x8*)(bhp + 4096 + nt * 512);
                if (t2 == 0)
                    acc_h0[nt] = __builtin_amdgcn_mfma_f32_16x16x32_f16(ahi, bh, acc_h0[nt], 0, 0, 0);
                else
                    acc_h1[nt] = __builtin_amdgcn_mfma_f32_16x16x32_f16(ahi, bh, acc_h1[nt], 0, 0, 0);
                acc_m[nt]  = __builtin_amdgcn_mfma_f32_16x16x32_f16(ahi, bl, acc_m[nt], 0, 0, 0);
                acc_m[nt]  = __builtin_amdgcn_mfma_f32_16x16x32_f16(alo, bh, acc_m[nt], 0, 0, 0);
                acc_ll[nt] = __builtin_amdgcn_mfma_f32_16x16x32_f16(alo, bl, acc_ll[nt], 0, 0, 0);
            }
        }
        __syncthreads();   // drains vmcnt(0): next chunk staged; cur buffer free
    }

    // LN1 stats: reduce over the 4 lane-groups sharing a row (xor 16,32)
    sum   += __shfl_xor(sum, 16);   sum   += __shfl_xor(sum, 32);
    sumsq += __shfl_xor(sumsq, 16); sumsq += __shfl_xor(sumsq, 32);
    float mu   = sum * (1.f / 1024.f);
    float var  = sumsq * (1.f / 1024.f) - mu * mu;
    float rstd = rsqrtf(var + LN_EPS);

    float uv[4], vv[4], g2v[4], b2v[4];
#pragma unroll
    for (int nt = 0; nt < 4; ++nt) {
        int bitc = nt * 16 + r16;
        uv[nt] = u[bitc]; vv[nt] = v[bitc]; g2v[nt] = g2[bitc]; b2v[nt] = b2[bitc];
    }
    float mu_m[4], rs_m[4];
#pragma unroll
    for (int reg = 0; reg < 4; ++reg) {
        int m = g * 4 + reg;
        mu_m[reg] = __shfl(mu, m);
        rs_m[reg] = __shfl(rstd, m);
    }

    float lg[4][4];  // [nt][reg]
#pragma unroll
    for (int nt = 0; nt < 4; ++nt)
#pragma unroll
        for (int reg = 0; reg < 4; ++reg) {
            float dot = (acc_h0[nt][reg] + acc_h1[nt][reg])
                      + acc_m[nt][reg] * (1.0f / 2048.0f)
                      + acc_ll[nt][reg] * (1.0f / 4194304.0f);
            lg[nt][reg] = rs_m[reg] * dot - rs_m[reg] * mu_m[reg] * uv[nt] + vv[nt];
        }

    // LN2 over the 64 bits of each row
#pragma unroll
    for (int reg = 0; reg < 4; ++reg) {
        float s1 = lg[0][reg] + lg[1][reg] + lg[2][reg] + lg[3][reg];
        float s2 = lg[0][reg]*lg[0][reg] + lg[1][reg]*lg[1][reg]
                 + lg[2][reg]*lg[2][reg] + lg[3][reg]*lg[3][reg];
#pragma unroll
        for (int m = 1; m <= 8; m <<= 1) {
            s1 += __shfl_xor(s1, m);
            s2 += __shfl_xor(s2, m);
        }
        float mean = s1 * (1.f / 64.f);
        float va   = s2 * (1.f / 64.f) - mean * mean;
        float rs2  = rsqrtf(va + LN_EPS);
#pragma unroll
        for (int nt = 0; nt < 4; ++nt)
            lg[nt][reg] = (lg[nt][reg] - mean) * rs2 * g2v[nt] + b2v[nt];
    }

    // store LN2'd logits
#pragma unroll
    for (int reg = 0; reg < 4; ++reg) {
        size_t row = (size_t)(row_base + g * 4 + reg);
#pragma unroll
        for (int nt = 0; nt < 4; ++nt)
            L[row * 64 + nt * 16 + r16] = lg[nt][reg];
    }

    // per-wave column partial sums (for batch mean)
#pragma unroll
    for (int nt = 0; nt < 4; ++nt) {
        float cs = lg[nt][0] + lg[nt][1] + lg[nt][2] + lg[nt][3];
        cs += __shfl_xor(cs, 16);
        cs += __shfl_xor(cs, 32);
        if (g == 0)
            P[((size_t)blockIdx.x * 4 + wid) * 64 + nt * 16 + r16] = cs;
    }
}

// ---------------- kernel 2: reduce column partials -> column means ----------------
__global__ void reduce_kernel(const float* __restrict__ P, float* __restrict__ cm) {
    int bit = blockIdx.x, t = threadIdx.x;
    float s = 0.f;
    for (int p = t; p < 4096; p += 256) s += P[(size_t)p * 64 + bit];
    __shared__ float sh[256];
    sh[t] = s;
    __syncthreads();
    for (int off = 128; off > 0; off >>= 1) {
        if (t < off) sh[t] += sh[t + off];
        __syncthreads();
    }
    if (t == 0) cm[bit] = sh[0] * (1.f / (float)N_ROWS);
}

// ---------------- kernel 3: mean-center + tanh + binarize ----------------
// L lives in the B-half of d_out; each element is read once then overwritten
// by the same thread in the same iteration (deterministic, replay-safe).
__global__ void final_kernel(const float* __restrict__ L, const float* __restrict__ cm,
                             float* __restrict__ out) {
    __shared__ float cms[64];
    if (threadIdx.x < 64) cms[threadIdx.x] = cm[threadIdx.x];
    __syncthreads();
    const float4* L4 = (const float4*)L;
    float4* H4 = (float4*)out;
    float4* B4 = (float4*)(out + (size_t)N_ROWS * NBIT);
    int total = N_ROWS * NBIT / 4;
    for (int i = blockIdx.x * blockDim.x + threadIdx.x; i < total;
         i += gridDim.x * blockDim.x) {
        float4 x = L4[i];
        int bb = (i & 15) * 4;
        float4 h, bo;
        h.x = tanhf(0.5f * (x.x - cms[bb + 0]));
        h.y = tanhf(0.5f * (x.y - cms[bb + 1]));
        h.z = tanhf(0.5f * (x.z - cms[bb + 2]));
        h.w = tanhf(0.5f * (x.w - cms[bb + 3]));
        bo.x = h.x >= 0.f ? 1.f : -1.f;
        bo.y = h.y >= 0.f ? 1.f : -1.f;
        bo.z = h.z >= 0.f ? 1.f : -1.f;
        bo.w = h.w >= 0.f ? 1.f : -1.f;
        H4[i] = h;
        B4[i] = bo;
    }
}

extern "C" void kernel_launch(void* const* d_in, const int* in_sizes, int n_in,
                              void* d_out, int out_size, void* d_ws, size_t ws_size,
                              hipStream_t stream) {
    (void)in_sizes; (void)n_in; (void)out_size; (void)ws_size;
    const float* X  = (const float*)d_in[0];
    const float* W  = (const float*)d_in[1];
    const float* bb = (const float*)d_in[2];
    const float* g1 = (const float*)d_in[3];
    const float* b1 = (const float*)d_in[4];
    const float* g2 = (const float*)d_in[5];
    const float* b2 = (const float*)d_in[6];

    char* ws = (char*)d_ws;
    _Float16* whi = (_Float16*)ws;                 // 128 KiB
    _Float16* wlo = (_Float16*)(ws + 131072);      // 128 KiB
    float* u  = (float*)(ws + 262144);             // 256 B
    float* v  = (float*)(ws + 266240);             // 256 B
    float* P  = (float*)(ws + 270336);             // 1 MiB (4096*64*4)
    float* cm = (float*)(ws + 270336 + 4096 * 64 * 4);

    float* out = (float*)d_out;
    float* L   = out + (size_t)N_ROWS * NBIT;      // reuse B-half of d_out as logit scratch

    prep_kernel<<<64, 256, 0, stream>>>(W, bb, g1, b1, whi, wlo, u, v);
    main_kernel<<<1024, 256, 0, stream>>>(X, whi, wlo, u, v, g2, b2, L, P);
    reduce_kernel<<<64, 256, 0, stream>>>(P, cm);
    final_kernel<<<2048, 256, 0, stream>>>(L, cm, out);
}